// Round 7
// baseline (238.269 us; speedup 1.0000x reference)
//
#include <hip/hip_runtime.h>
#include <hip/hip_bf16.h>
#include <math.h>

#define NN 50000
#define NE 800000
#define NBK 196          // buckets = (NN+255)/256, bucket = dst>>8
#define CHUNK 8192
#define NCH ((NE + CHUNK - 1) / CHUNK)   // 98
#define APITCH 136       // padded bf16 row pitch for gemm1 A-tile

typedef short bf16x8 __attribute__((ext_vector_type(8)));
typedef float f32x4  __attribute__((ext_vector_type(4)));

// ---------- bf16 pack/unpack helpers (internal storage only) ----------
__device__ __forceinline__ unsigned short f2bf(float f) {
    union { float f; unsigned int i; } v; v.f = f;
    unsigned int x = v.i;
    unsigned int r = (x >> 16) & 1u;          // round-to-nearest-even
    x += 0x7fffu + r;
    return (unsigned short)(x >> 16);
}
__device__ __forceinline__ void un2(unsigned int u, float& a, float& b) {
    union { unsigned int i; float f; } x, y;
    x.i = u << 16; y.i = u & 0xffff0000u;
    a = x.f; b = y.f;
}

// ---------- CSR build: bucket-partitioned counting sort ----------
__global__ __launch_bounds__(256) void k_bhist(const int* __restrict__ ei,
                                               int* __restrict__ bhist) {
    __shared__ int h[NBK];
    int t = threadIdx.x;
    if (t < NBK) h[t] = 0;
    __syncthreads();
    int cb = blockIdx.x * CHUNK;
#pragma unroll
    for (int k = 0; k < CHUNK / 256; k++) {
        int i = cb + k * 256 + t;
        if (i < NE) atomicAdd(&h[ei[NE + i] >> 8], 1);
    }
    __syncthreads();
    if (t < NBK && h[t]) atomicAdd(&bhist[t], h[t]);
}

__global__ __launch_bounds__(256) void k_bkscan(const int* __restrict__ bhist,
                                                int* __restrict__ bbase,
                                                int* __restrict__ gcur) {
    __shared__ int tmp[256];
    int t = threadIdx.x;
    int v = (t < NBK) ? bhist[t] : 0;
    tmp[t] = v;
    __syncthreads();
    for (int off = 1; off < 256; off <<= 1) {
        int u = (t >= off) ? tmp[t - off] : 0;
        __syncthreads();
        tmp[t] += u;
        __syncthreads();
    }
    if (t < NBK) { int e = tmp[t] - v; bbase[t] = e; gcur[t] = e; }
}

__global__ __launch_bounds__(256) void k_bin(const int* __restrict__ ei,
                                             int* __restrict__ gcur,
                                             unsigned int* __restrict__ packed) {
    __shared__ int h[NBK];
    __shared__ int bas[NBK];
    int t = threadIdx.x;
    if (t < NBK) h[t] = 0;
    __syncthreads();
    int cb = blockIdx.x * CHUNK;
#pragma unroll
    for (int k = 0; k < CHUNK / 256; k++) {
        int i = cb + k * 256 + t;
        if (i < NE) atomicAdd(&h[ei[NE + i] >> 8], 1);
    }
    __syncthreads();
    if (t < NBK) {
        int c = h[t];
        bas[t] = c ? atomicAdd(&gcur[t], c) : 0;
        h[t] = 0;
    }
    __syncthreads();
#pragma unroll
    for (int k = 0; k < CHUNK / 256; k++) {
        int i = cb + k * 256 + t;
        if (i < NE) {
            int s = ei[i], d = ei[NE + i];
            int b = d >> 8;
            int r = atomicAdd(&h[b], 1);
            packed[bas[b] + r] = (unsigned int)s | ((unsigned int)(d & 255) << 16);
        }
    }
}

__global__ __launch_bounds__(256) void k_final(const unsigned int* __restrict__ packed,
                                               const int* __restrict__ bbase,
                                               int* __restrict__ deg,
                                               int* __restrict__ offs,
                                               int* __restrict__ ssrc) {
    __shared__ unsigned int pk[8192];   // 32 KB
    __shared__ int osl[8192];           // 32 KB
    __shared__ int cnt[256], pre[256], cur[256];
    int t = threadIdx.x, b = blockIdx.x;
    int start = bbase[b];
    int end = (b + 1 < NBK) ? bbase[b + 1] : NE;
    int n = end - start;
    for (int i = t; i < n; i += 256) pk[i] = packed[start + i];
    cnt[t] = 0;
    __syncthreads();
    for (int i = t; i < n; i += 256) atomicAdd(&cnt[(pk[i] >> 16) & 255], 1);
    __syncthreads();
    int v = cnt[t];
    pre[t] = v;
    __syncthreads();
    for (int off = 1; off < 256; off <<= 1) {
        int u = (t >= off) ? pre[t - off] : 0;
        __syncthreads();
        pre[t] += u;
        __syncthreads();
    }
    int excl = pre[t] - v;
    int dst = b * 256 + t;
    if (dst < NN) { deg[dst] = v; offs[dst] = start + excl; }
    cur[t] = excl;
    __syncthreads();
    for (int i = t; i < n; i += 256) {
        unsigned int p = pk[i];
        int r = atomicAdd(&cur[(p >> 16) & 255], 1);
        osl[r] = (int)(p & 0xffffu);
    }
    __syncthreads();
    for (int i = t; i < n; i += 256) ssrc[start + i] = osl[i];
}

// ---------- W1 -> B-fragment-major bf16 swizzle (once, 8 blocks) ----------
__global__ __launch_bounds__(256) void k_swizw(const float* __restrict__ W1,
                                               uint4* __restrict__ W1s) {
    int f = blockIdx.x * 256 + threadIdx.x;   // [0,2048)
    int nt = f >> 8, kc = (f >> 6) & 3, l = f & 63;
    int n  = nt * 16 + (l & 15);
    int k0 = kc * 32 + (l >> 4) * 8;
    unsigned int p[4];
#pragma unroll
    for (int jj = 0; jj < 4; jj++) {
        float v0 = W1[(k0 + 2 * jj) * 128 + n];
        float v1 = W1[(k0 + 2 * jj + 1) * 128 + n];
        p[jj] = (unsigned int)f2bf(v0) | ((unsigned int)f2bf(v1) << 16);
    }
    W1s[f] = make_uint4(p[0], p[1], p[2], p[3]);
}

// ---------- Layer 1 GEMM via MFMA ----------
__global__ __launch_bounds__(256) void k_gemm1(
    const float* __restrict__ x,      // [NN,128] fp32
    const uint4* __restrict__ W1s,    // swizzled bf16 fragments
    const float* __restrict__ aS,     // [8,16]
    const float* __restrict__ aD,     // [8,16]
    unsigned short* __restrict__ h1,  // [NN,128] bf16 out
    float* __restrict__ as1,          // [NN,8]
    float* __restrict__ ad1)          // [NN,8]
{
    __shared__ unsigned short Alds[64 * APITCH];   // 17408 B
    int t = threadIdx.x;
    int w = t >> 6, l = t & 63;
    int rowbase = blockIdx.x * 64;

    {
        const float4* xg = (const float4*)(x + (size_t)rowbase * 128);
#pragma unroll
        for (int i = 0; i < 8; i++) {
            int idx = t + 256 * i;             // float4 id [0,2048)
            int r = idx >> 5, c = (idx & 31) * 4;
            float4 v = make_float4(0.f, 0.f, 0.f, 0.f);
            if (rowbase + r < NN) v = xg[idx];
            unsigned int p0 = (unsigned int)f2bf(v.x) | ((unsigned int)f2bf(v.y) << 16);
            unsigned int p1 = (unsigned int)f2bf(v.z) | ((unsigned int)f2bf(v.w) << 16);
            *(uint2*)&Alds[r * APITCH + c] = make_uint2(p0, p1);
        }
    }

    union BU { uint4 u; bf16x8 v; };
    BU b[2][4];
#pragma unroll
    for (int j = 0; j < 2; j++) {
        int nt = 2 * w + j;
#pragma unroll
        for (int kc = 0; kc < 4; kc++)
            b[j][kc].u = W1s[(nt * 4 + kc) * 64 + l];
    }
    __syncthreads();

    f32x4 acc[4][2];
#pragma unroll
    for (int mt = 0; mt < 4; mt++)
#pragma unroll
        for (int j = 0; j < 2; j++) acc[mt][j] = (f32x4){0.f, 0.f, 0.f, 0.f};

    int mrow = l & 15, quad = l >> 4;
#pragma unroll
    for (int kc = 0; kc < 4; kc++) {
#pragma unroll
        for (int mt = 0; mt < 4; mt++) {
            bf16x8 a = *(const bf16x8*)&Alds[(mt * 16 + mrow) * APITCH + kc * 32 + quad * 8];
            acc[mt][0] = __builtin_amdgcn_mfma_f32_16x16x32_bf16(a, b[0][kc].v, acc[mt][0], 0, 0, 0);
            acc[mt][1] = __builtin_amdgcn_mfma_f32_16x16x32_bf16(a, b[1][kc].v, acc[mt][1], 0, 0, 0);
        }
    }

#pragma unroll
    for (int j = 0; j < 2; j++) {
        int head = 2 * w + j;
        float aSv = aS[head * 16 + mrow];
        float aDv = aD[head * 16 + mrow];
#pragma unroll
        for (int mt = 0; mt < 4; mt++) {
#pragma unroll
            for (int reg = 0; reg < 4; reg++) {
                float s = acc[mt][j][reg] * aSv;
                float d = acc[mt][j][reg] * aDv;
                s += __shfl_xor(s, 1); s += __shfl_xor(s, 2);
                s += __shfl_xor(s, 4); s += __shfl_xor(s, 8);
                d += __shfl_xor(d, 1); d += __shfl_xor(d, 2);
                d += __shfl_xor(d, 4); d += __shfl_xor(d, 8);
                if (mrow == 0) {
                    int grow = rowbase + mt * 16 + quad * 4 + reg;
                    if (grow < NN) {
                        as1[grow * 8 + head] = s;
                        ad1[grow * 8 + head] = d;
                    }
                }
            }
        }
    }

    __syncthreads();   // A reads done; reuse Alds for C transpose
#pragma unroll
    for (int mt = 0; mt < 4; mt++)
#pragma unroll
        for (int j = 0; j < 2; j++) {
            int col = w * 32 + j * 16 + mrow;
#pragma unroll
            for (int reg = 0; reg < 4; reg++) {
                int r = mt * 16 + quad * 4 + reg;
                Alds[r * APITCH + col] = f2bf(acc[mt][j][reg]);
            }
        }
    __syncthreads();
    uint4* hg = (uint4*)h1;   // 16 uint4 per 128-col row
#pragma unroll
    for (int i = 0; i < 4; i++) {
        int idx = t + 256 * i;           // uint4 id [0,1024)
        int r = idx >> 4, ci = idx & 15;
        if (rowbase + r < NN)
            hg[(size_t)(rowbase + r) * 16 + ci] = *(const uint4*)&Alds[r * APITCH + ci * 8];
    }
}

// ---------- Layer 1 aggregation + FUSED layer-2 GEMM epilogue ----------
// One wave per node. lane = jg*16 + li: jg = edge group [0,4), li = 16B chunk [0,16).
// Epilogue: all lanes hold the reduced h2 row chunk (butterfly); lane computes
// g2 partial for cols [4jg,4jg+4) from its 8 h2 cols, reduced over li.
__global__ __launch_bounds__(256) void k_agg1(
    const int* __restrict__ offs, const int* __restrict__ deg,
    const int* __restrict__ ssrc,
    const float* __restrict__ as1, const float* __restrict__ ad1,
    const unsigned short* __restrict__ h1, const float* __restrict__ b1,
    const float* __restrict__ W2, const float* __restrict__ aS2,
    const float* __restrict__ aD2,
    float* __restrict__ g2, float* __restrict__ as2, float* __restrict__ ad2)
{
    __shared__ float W2l[128 * 17];   // pitch 17: 4-way instead of 16-way conflicts
    int t = threadIdx.x;
    for (int i = t; i < 2048; i += 256) W2l[(i >> 4) * 17 + (i & 15)] = W2[i];
    __syncthreads();

    int wave = t >> 6;
    int lane = t & 63;
    int node = blockIdx.x * 4 + wave;
    if (node >= NN) return;
    int start = offs[node], cnt = deg[node];

    int li = lane & 15, jg = lane >> 4;
    int head = li >> 1;
    float adv = ad1[node * 8 + head];

    const uint4* h1u4 = (const uint4*)h1;
    float acc[8];
#pragma unroll
    for (int i = 0; i < 8; i++) acc[i] = 0.f;
    float dsum = 0.f;

    for (int base = 0; base <= cnt; base += 16) {    // 4 x 4 edges in flight
#pragma unroll
        for (int u = 0; u < 4; u++) {
            int j = base + u * 4 + jg;
            if (j <= cnt) {
                int s = (j < cnt) ? ssrc[start + j] : node;   // j==cnt -> self loop
                float e = as1[s * 8 + head] + adv;
                e = (e > 0.f) ? e : 0.2f * e;
                float w = __expf(e);
                uint4 hv = h1u4[(size_t)s * 16 + li];
                float f0, f1, f2, f3, f4, f5, f6, f7;
                un2(hv.x, f0, f1); un2(hv.y, f2, f3);
                un2(hv.z, f4, f5); un2(hv.w, f6, f7);
                acc[0] += w * f0; acc[1] += w * f1; acc[2] += w * f2; acc[3] += w * f3;
                acc[4] += w * f4; acc[5] += w * f5; acc[6] += w * f6; acc[7] += w * f7;
                if ((li & 1) == 0) dsum += w;
            }
        }
    }

    // butterfly: ALL lanes end up with the full sums for their li chunk
#pragma unroll
    for (int i = 0; i < 8; i++) {
        acc[i] += __shfl_xor(acc[i], 16);
        acc[i] += __shfl_xor(acc[i], 32);
    }
    dsum += __shfl_xor(dsum, 16);
    dsum += __shfl_xor(dsum, 32);
    dsum += __shfl_xor(dsum, 1);

    // h2 row chunk in fp32 registers (never touches memory)
    float inv = 1.0f / dsum;
    int c0 = li * 8;
    float v[8];
#pragma unroll
    for (int i = 0; i < 8; i++) {
        float vv = acc[i] * inv + b1[c0 + i];
        v[i] = (vv > 0.f) ? vv : (__expf(vv) - 1.0f);   // ELU
    }

    // fused gemm2: outputs [4jg, 4jg+4)
    int n0 = jg * 4;
    float p0 = 0.f, p1 = 0.f, p2 = 0.f, p3 = 0.f;
#pragma unroll
    for (int i = 0; i < 8; i++) {
        const float* wr = &W2l[(c0 + i) * 17 + n0];
        float hv = v[i];
        p0 += hv * wr[0]; p1 += hv * wr[1]; p2 += hv * wr[2]; p3 += hv * wr[3];
    }
#pragma unroll
    for (int m = 1; m < 16; m <<= 1) {
        p0 += __shfl_xor(p0, m); p1 += __shfl_xor(p1, m);
        p2 += __shfl_xor(p2, m); p3 += __shfl_xor(p3, m);
    }
    // alpha scalars for layer 2
    float s2 = p0 * aS2[n0] + p1 * aS2[n0 + 1] + p2 * aS2[n0 + 2] + p3 * aS2[n0 + 3];
    float d2 = p0 * aD2[n0] + p1 * aD2[n0 + 1] + p2 * aD2[n0 + 2] + p3 * aD2[n0 + 3];
    s2 += __shfl_xor(s2, 16); s2 += __shfl_xor(s2, 32);
    d2 += __shfl_xor(d2, 16); d2 += __shfl_xor(d2, 32);

    if (li == 0) ((float4*)g2)[(size_t)node * 4 + jg] = make_float4(p0, p1, p2, p3);
    if (lane == 0) { as2[node] = s2; ad2[node] = d2; }
}

// ---------- Layer 2 aggregation ----------
__global__ __launch_bounds__(256) void k_agg2(
    const int* __restrict__ offs, const int* __restrict__ deg,
    const int* __restrict__ ssrc,
    const float* __restrict__ as2, const float* __restrict__ ad2,
    const float* __restrict__ g2, const float* __restrict__ b2,
    float* __restrict__ out)
{
    int wave = threadIdx.x >> 6;
    int lane = threadIdx.x & 63;
    int node = blockIdx.x * 4 + wave;
    if (node >= NN) return;
    int start = offs[node], cnt = deg[node];
    float adv = ad2[node];

    int li4 = lane & 3, jg = lane >> 2;
    const float4* g2f4 = (const float4*)g2;

    float a0 = 0.f, a1 = 0.f, a2 = 0.f, a3 = 0.f, dsum = 0.f;
    for (int base = 0; base <= cnt; base += 16) {
        int j = base + jg;
        if (j <= cnt) {
            int s = (j < cnt) ? ssrc[start + j] : node;
            float e = as2[s] + adv;
            e = (e > 0.f) ? e : 0.2f * e;
            float w = __expf(e);
            float4 g = g2f4[(size_t)s * 4 + li4];
            a0 += w * g.x; a1 += w * g.y; a2 += w * g.z; a3 += w * g.w;
            if (li4 == 0) dsum += w;
        }
    }
#pragma unroll
    for (int m = 4; m < 64; m <<= 1) {
        a0 += __shfl_xor(a0, m); a1 += __shfl_xor(a1, m);
        a2 += __shfl_xor(a2, m); a3 += __shfl_xor(a3, m);
        dsum += __shfl_xor(dsum, m);
    }
    dsum += __shfl_xor(dsum, 1);
    dsum += __shfl_xor(dsum, 2);   // broadcast denom to all li4

    if (jg == 0) {
        float inv = 1.0f / dsum;
        const float4* b2f4 = (const float4*)b2;
        float4 bb = b2f4[li4];
        float4 o = make_float4(a0 * inv + bb.x, a1 * inv + bb.y,
                               a2 * inv + bb.z, a3 * inv + bb.w);
        ((float4*)out)[(size_t)node * 4 + li4] = o;
    }
}

// ---------- launch ----------
extern "C" void kernel_launch(void* const* d_in, const int* in_sizes, int n_in,
                              void* d_out, int out_size, void* d_ws, size_t ws_size,
                              hipStream_t stream) {
    const float* x   = (const float*)d_in[0];
    const int*   ei  = (const int*)d_in[1];
    const float* W1  = (const float*)d_in[2];
    const float* aS1 = (const float*)d_in[3];
    const float* aD1 = (const float*)d_in[4];
    const float* b1  = (const float*)d_in[5];
    const float* W2  = (const float*)d_in[6];
    const float* aS2 = (const float*)d_in[7];
    const float* aD2 = (const float*)d_in[8];
    const float* b2  = (const float*)d_in[9];

    char* ws = (char*)d_ws;
    size_t off = 0;
    auto alloc = [&](size_t bytes) { void* p = ws + off; off += (bytes + 255) & ~(size_t)255; return p; };

    unsigned short* h1 = (unsigned short*)alloc((size_t)NN * 128 * 2);  // bf16
    float* as1 = (float*)alloc((size_t)NN * 8 * 4);
    float* ad1 = (float*)alloc((size_t)NN * 8 * 4);
    float* g2  = (float*)alloc((size_t)NN * 16 * 4);
    float* as2 = (float*)alloc((size_t)NN * 4);
    float* ad2 = (float*)alloc((size_t)NN * 4);
    int* deg    = (int*)alloc((size_t)NN * 4);
    int* offs   = (int*)alloc((size_t)NN * 4);
    int* ssrc   = (int*)alloc((size_t)NE * 4);
    unsigned int* packed = (unsigned int*)alloc((size_t)NE * 4);
    int* bhist  = (int*)alloc((size_t)NBK * 4);
    int* bbase  = (int*)alloc((size_t)NBK * 4);
    int* gcur   = (int*)alloc((size_t)NBK * 4);
    uint4* W1s  = (uint4*)alloc((size_t)2048 * 16);   // swizzled bf16 W1

    hipMemsetAsync(bhist, 0, (size_t)NBK * 4, stream);
    k_bhist<<<NCH, 256, 0, stream>>>(ei, bhist);
    k_bkscan<<<1, 256, 0, stream>>>(bhist, bbase, gcur);
    k_bin<<<NCH, 256, 0, stream>>>(ei, gcur, packed);
    k_final<<<NBK, 256, 0, stream>>>(packed, bbase, deg, offs, ssrc);

    k_swizw<<<8, 256, 0, stream>>>(W1, W1s);
    k_gemm1<<<(NN + 63) / 64, 256, 0, stream>>>(x, W1s, aS1, aD1, h1, as1, ad1);
    k_agg1<<<(NN + 3) / 4, 256, 0, stream>>>(offs, deg, ssrc, as1, ad1, h1, b1,
                                             W2, aS2, aD2, g2, as2, ad2);
    k_agg2<<<(NN + 3) / 4, 256, 0, stream>>>(offs, deg, ssrc, as2, ad2, g2, b2,
                                             (float*)d_out);
}

// Round 8
// 217.934 us; speedup vs baseline: 1.0933x; 1.0933x over previous
//
#include <hip/hip_runtime.h>
#include <hip/hip_bf16.h>
#include <math.h>

#define NN 50000
#define NE 800000
#define NBK 196          // buckets = (NN+255)/256, bucket = dst>>8
#define BCAP 5120        // fixed bucket capacity (mean 4096, sigma~64 -> 16 sigma)
#define CHUNK 8192
#define NCH ((NE + CHUNK - 1) / CHUNK)   // 98
#define APITCH 136       // padded bf16 row pitch for gemm1 A-tile

typedef short bf16x8 __attribute__((ext_vector_type(8)));
typedef float f32x4  __attribute__((ext_vector_type(4)));
typedef float f32x2  __attribute__((ext_vector_type(2)));

// ---------- bf16 pack/unpack helpers (internal storage only) ----------
__device__ __forceinline__ unsigned short f2bf(float f) {
    union { float f; unsigned int i; } v; v.f = f;
    unsigned int x = v.i;
    unsigned int r = (x >> 16) & 1u;          // round-to-nearest-even
    x += 0x7fffu + r;
    return (unsigned short)(x >> 16);
}
__device__ __forceinline__ void un2(unsigned int u, float& a, float& b) {
    union { unsigned int i; float f; } x, y;
    x.i = u << 16; y.i = u & 0xffff0000u;
    a = x.f; b = y.f;
}
__device__ __forceinline__ f32x2 up2(unsigned int u) {
    union { unsigned int i; float f; } x, y;
    x.i = u << 16; y.i = u & 0xffff0000u;
    return (f32x2){x.f, y.f};
}

// ---------- CSR build: fixed-capacity bucket sort (2 kernels) ----------
__global__ __launch_bounds__(256) void k_bin(const int* __restrict__ ei,
                                             int* __restrict__ gcur,
                                             unsigned int* __restrict__ packed) {
    __shared__ int h[NBK];
    __shared__ int bas[NBK];
    int t = threadIdx.x;
    if (t < NBK) h[t] = 0;
    __syncthreads();
    int cb = blockIdx.x * CHUNK;
#pragma unroll
    for (int k = 0; k < CHUNK / 256; k++) {
        int i = cb + k * 256 + t;
        if (i < NE) atomicAdd(&h[ei[NE + i] >> 8], 1);
    }
    __syncthreads();
    if (t < NBK) {
        int c = h[t];
        bas[t] = c ? (t * BCAP + atomicAdd(&gcur[t], c)) : 0;
        h[t] = 0;
    }
    __syncthreads();
#pragma unroll
    for (int k = 0; k < CHUNK / 256; k++) {
        int i = cb + k * 256 + t;
        if (i < NE) {
            int s = ei[i], d = ei[NE + i];
            int b = d >> 8;
            int r = atomicAdd(&h[b], 1);
            packed[bas[b] + r] = (unsigned int)s | ((unsigned int)(d & 255) << 16);
        }
    }
}

__global__ __launch_bounds__(256) void k_final(const unsigned int* __restrict__ packed,
                                               const int* __restrict__ gcur,
                                               int* __restrict__ deg,
                                               int* __restrict__ offs,
                                               int* __restrict__ ssrc) {
    __shared__ unsigned int pk[BCAP + 64];
    __shared__ int osl[BCAP + 64];
    __shared__ int cnt[256], pre[256], cur[256];
    int t = threadIdx.x, b = blockIdx.x;
    int start = b * BCAP;
    int n = gcur[b];
    for (int i = t; i < n; i += 256) pk[i] = packed[start + i];
    cnt[t] = 0;
    __syncthreads();
    for (int i = t; i < n; i += 256) atomicAdd(&cnt[(pk[i] >> 16) & 255], 1);
    __syncthreads();
    int v = cnt[t];
    pre[t] = v;
    __syncthreads();
    for (int off = 1; off < 256; off <<= 1) {
        int u = (t >= off) ? pre[t - off] : 0;
        __syncthreads();
        pre[t] += u;
        __syncthreads();
    }
    int excl = pre[t] - v;
    int dst = b * 256 + t;
    if (dst < NN) { deg[dst] = v; offs[dst] = start + excl; }
    cur[t] = excl;
    __syncthreads();
    for (int i = t; i < n; i += 256) {
        unsigned int p = pk[i];
        int r = atomicAdd(&cur[(p >> 16) & 255], 1);
        osl[r] = (int)(p & 0xffffu);
    }
    __syncthreads();
    for (int i = t; i < n; i += 256) ssrc[start + i] = osl[i];
}

// ---------- W1 -> B-fragment-major bf16 swizzle (once, 8 blocks) ----------
__global__ __launch_bounds__(256) void k_swizw(const float* __restrict__ W1,
                                               uint4* __restrict__ W1s) {
    int f = blockIdx.x * 256 + threadIdx.x;   // [0,2048)
    int nt = f >> 8, kc = (f >> 6) & 3, l = f & 63;
    int n  = nt * 16 + (l & 15);
    int k0 = kc * 32 + (l >> 4) * 8;
    unsigned int p[4];
#pragma unroll
    for (int jj = 0; jj < 4; jj++) {
        float v0 = W1[(k0 + 2 * jj) * 128 + n];
        float v1 = W1[(k0 + 2 * jj + 1) * 128 + n];
        p[jj] = (unsigned int)f2bf(v0) | ((unsigned int)f2bf(v1) << 16);
    }
    W1s[f] = make_uint4(p[0], p[1], p[2], p[3]);
}

// ---------- Layer 1 GEMM via MFMA ----------
__global__ __launch_bounds__(256) void k_gemm1(
    const float* __restrict__ x,      // [NN,128] fp32
    const uint4* __restrict__ W1s,    // swizzled bf16 fragments
    const float* __restrict__ aS,     // [8,16]
    const float* __restrict__ aD,     // [8,16]
    unsigned short* __restrict__ h1,  // [NN,128] bf16 out
    float* __restrict__ as1,          // [NN,8]
    float* __restrict__ ad1)          // [NN,8]
{
    __shared__ unsigned short Alds[64 * APITCH];   // 17408 B
    int t = threadIdx.x;
    int w = t >> 6, l = t & 63;
    int rowbase = blockIdx.x * 64;

    {
        const float4* xg = (const float4*)(x + (size_t)rowbase * 128);
#pragma unroll
        for (int i = 0; i < 8; i++) {
            int idx = t + 256 * i;             // float4 id [0,2048)
            int r = idx >> 5, c = (idx & 31) * 4;
            float4 v = make_float4(0.f, 0.f, 0.f, 0.f);
            if (rowbase + r < NN) v = xg[idx];
            unsigned int p0 = (unsigned int)f2bf(v.x) | ((unsigned int)f2bf(v.y) << 16);
            unsigned int p1 = (unsigned int)f2bf(v.z) | ((unsigned int)f2bf(v.w) << 16);
            *(uint2*)&Alds[r * APITCH + c] = make_uint2(p0, p1);
        }
    }

    union BU { uint4 u; bf16x8 v; };
    BU b[2][4];
#pragma unroll
    for (int j = 0; j < 2; j++) {
        int nt = 2 * w + j;
#pragma unroll
        for (int kc = 0; kc < 4; kc++)
            b[j][kc].u = W1s[(nt * 4 + kc) * 64 + l];
    }
    __syncthreads();

    f32x4 acc[4][2];
#pragma unroll
    for (int mt = 0; mt < 4; mt++)
#pragma unroll
        for (int j = 0; j < 2; j++) acc[mt][j] = (f32x4){0.f, 0.f, 0.f, 0.f};

    int mrow = l & 15, quad = l >> 4;
#pragma unroll
    for (int kc = 0; kc < 4; kc++) {
#pragma unroll
        for (int mt = 0; mt < 4; mt++) {
            bf16x8 a = *(const bf16x8*)&Alds[(mt * 16 + mrow) * APITCH + kc * 32 + quad * 8];
            acc[mt][0] = __builtin_amdgcn_mfma_f32_16x16x32_bf16(a, b[0][kc].v, acc[mt][0], 0, 0, 0);
            acc[mt][1] = __builtin_amdgcn_mfma_f32_16x16x32_bf16(a, b[1][kc].v, acc[mt][1], 0, 0, 0);
        }
    }

#pragma unroll
    for (int j = 0; j < 2; j++) {
        int head = 2 * w + j;
        float aSv = aS[head * 16 + mrow];
        float aDv = aD[head * 16 + mrow];
#pragma unroll
        for (int mt = 0; mt < 4; mt++) {
#pragma unroll
            for (int reg = 0; reg < 4; reg++) {
                float s = acc[mt][j][reg] * aSv;
                float d = acc[mt][j][reg] * aDv;
                s += __shfl_xor(s, 1); s += __shfl_xor(s, 2);
                s += __shfl_xor(s, 4); s += __shfl_xor(s, 8);
                d += __shfl_xor(d, 1); d += __shfl_xor(d, 2);
                d += __shfl_xor(d, 4); d += __shfl_xor(d, 8);
                if (mrow == 0) {
                    int grow = rowbase + mt * 16 + quad * 4 + reg;
                    if (grow < NN) {
                        as1[grow * 8 + head] = s;
                        ad1[grow * 8 + head] = d;
                    }
                }
            }
        }
    }

    __syncthreads();   // A reads done; reuse Alds for C transpose
#pragma unroll
    for (int mt = 0; mt < 4; mt++)
#pragma unroll
        for (int j = 0; j < 2; j++) {
            int col = w * 32 + j * 16 + mrow;
#pragma unroll
            for (int reg = 0; reg < 4; reg++) {
                int r = mt * 16 + quad * 4 + reg;
                Alds[r * APITCH + col] = f2bf(acc[mt][j][reg]);
            }
        }
    __syncthreads();
    uint4* hg = (uint4*)h1;   // 16 uint4 per 128-col row
#pragma unroll
    for (int i = 0; i < 4; i++) {
        int idx = t + 256 * i;           // uint4 id [0,1024)
        int r = idx >> 4, ci = idx & 15;
        if (rowbase + r < NN)
            hg[(size_t)(rowbase + r) * 16 + ci] = *(const uint4*)&Alds[r * APITCH + ci * 8];
    }
}

// ---------- Layer 1 aggregation: lane = jg*8 + li, li == head, 32B/lane ----------
// 8 jg edge-groups x 2 unroll = 16 edges in flight; f32x2 packed FMA accumulate.
__global__ __launch_bounds__(256) void k_agg1(
    const int* __restrict__ offs, const int* __restrict__ deg,
    const int* __restrict__ ssrc,
    const float* __restrict__ as1, const float* __restrict__ ad1,
    const unsigned short* __restrict__ h1, const float* __restrict__ b1,
    unsigned short* __restrict__ h2)
{
    int wave = threadIdx.x >> 6;
    int lane = threadIdx.x & 63;
    int node = blockIdx.x * 4 + wave;
    if (node >= NN) return;
    int start = offs[node], cnt = deg[node];

    int li = lane & 7, jg = lane >> 3;   // li = head, covers cols [li*16, li*16+16)
    float adv = ad1[node * 8 + li];

    const uint4* h1u4 = (const uint4*)h1;
    f32x2 acc[8];
#pragma unroll
    for (int i = 0; i < 8; i++) acc[i] = (f32x2){0.f, 0.f};
    float dsum = 0.f;

    for (int base = 0; base <= cnt; base += 16) {    // 2 x 8 edges in flight
#pragma unroll
        for (int u = 0; u < 2; u++) {
            int j = base + u * 8 + jg;
            if (j <= cnt) {
                int s = (j < cnt) ? ssrc[start + j] : node;   // j==cnt -> self loop
                float e = as1[s * 8 + li] + adv;
                e = (e > 0.f) ? e : 0.2f * e;
                float w = __expf(e);
                uint4 ha = h1u4[(size_t)s * 16 + 2 * li];
                uint4 hb = h1u4[(size_t)s * 16 + 2 * li + 1];
                f32x2 w2 = (f32x2){w, w};
                acc[0] += w2 * up2(ha.x); acc[1] += w2 * up2(ha.y);
                acc[2] += w2 * up2(ha.z); acc[3] += w2 * up2(ha.w);
                acc[4] += w2 * up2(hb.x); acc[5] += w2 * up2(hb.y);
                acc[6] += w2 * up2(hb.z); acc[7] += w2 * up2(hb.w);
                dsum += w;
            }
        }
    }

    // butterfly over the 8 jg groups (lanes with same li)
#pragma unroll
    for (int i = 0; i < 8; i++) {
        acc[i].x += __shfl_xor(acc[i].x, 8);  acc[i].y += __shfl_xor(acc[i].y, 8);
        acc[i].x += __shfl_xor(acc[i].x, 16); acc[i].y += __shfl_xor(acc[i].y, 16);
        acc[i].x += __shfl_xor(acc[i].x, 32); acc[i].y += __shfl_xor(acc[i].y, 32);
    }
    dsum += __shfl_xor(dsum, 8);
    dsum += __shfl_xor(dsum, 16);
    dsum += __shfl_xor(dsum, 32);

    if (jg == 0) {
        float inv = 1.0f / dsum;
        int c0 = li * 16;
        float v[16];
#pragma unroll
        for (int i = 0; i < 8; i++) {
            float v0 = acc[i].x * inv + b1[c0 + 2 * i];
            float v1 = acc[i].y * inv + b1[c0 + 2 * i + 1];
            v[2 * i]     = (v0 > 0.f) ? v0 : (__expf(v0) - 1.0f);   // ELU
            v[2 * i + 1] = (v1 > 0.f) ? v1 : (__expf(v1) - 1.0f);
        }
        uint4 o0, o1;
        o0.x = (unsigned int)f2bf(v[0])  | ((unsigned int)f2bf(v[1])  << 16);
        o0.y = (unsigned int)f2bf(v[2])  | ((unsigned int)f2bf(v[3])  << 16);
        o0.z = (unsigned int)f2bf(v[4])  | ((unsigned int)f2bf(v[5])  << 16);
        o0.w = (unsigned int)f2bf(v[6])  | ((unsigned int)f2bf(v[7])  << 16);
        o1.x = (unsigned int)f2bf(v[8])  | ((unsigned int)f2bf(v[9])  << 16);
        o1.y = (unsigned int)f2bf(v[10]) | ((unsigned int)f2bf(v[11]) << 16);
        o1.z = (unsigned int)f2bf(v[12]) | ((unsigned int)f2bf(v[13]) << 16);
        o1.w = (unsigned int)f2bf(v[14]) | ((unsigned int)f2bf(v[15]) << 16);
        ((uint4*)h2)[(size_t)node * 16 + 2 * li] = o0;
        ((uint4*)h2)[(size_t)node * 16 + 2 * li + 1] = o1;
    }
}

// ---------- Layer 2 GEMM ----------
__global__ __launch_bounds__(256) void k_gemm2(
    const unsigned short* __restrict__ h2,   // [NN,128] bf16
    const float* __restrict__ W2,            // [128,16] fp32
    const float* __restrict__ aS2,           // [16]
    const float* __restrict__ aD2,           // [16]
    float* __restrict__ g2,                  // [NN,16]
    float* __restrict__ as2, float* __restrict__ ad2)
{
    __shared__ float Wl[128 * 16];     // 8 KB
    __shared__ float xl[32 * 129];     // padded
    __shared__ float aSf[16], aDf[16];
    int t = threadIdx.x;

    for (int i = t; i < 2048; i += 256) Wl[i] = W2[i];
    if (t < 16) { aSf[t] = aS2[t]; aDf[t] = aD2[t]; }

    int rowbase = blockIdx.x * 32;
    for (int i = t; i < 2048; i += 256) {        // 32 rows * 64 uints
        int row = rowbase + (i >> 6);
        unsigned int u = (row < NN) ? ((const unsigned int*)h2)[(size_t)rowbase * 64 + i] : 0u;
        float a, b; un2(u, a, b);
        int lin = 2 * i;
        int rr = lin >> 7, kk = lin & 127;
        xl[rr * 129 + kk] = a;
        xl[rr * 129 + kk + 1] = b;
    }
    __syncthreads();

    int r = t >> 3, cp = t & 7;
    int row = rowbase + r;
    float a0 = 0.f, a1 = 0.f;
    const float* xrow = &xl[r * 129];
#pragma unroll 4
    for (int k = 0; k < 128; k++) {
        float xv = xrow[k];
        a0 += xv * Wl[k * 16 + 2 * cp];
        a1 += xv * Wl[k * 16 + 2 * cp + 1];
    }
    if (row < NN) ((float2*)g2)[(size_t)row * 8 + cp] = make_float2(a0, a1);

    float asp = a0 * aSf[2 * cp] + a1 * aSf[2 * cp + 1];
    float adp = a0 * aDf[2 * cp] + a1 * aDf[2 * cp + 1];
    asp += __shfl_xor(asp, 1); asp += __shfl_xor(asp, 2); asp += __shfl_xor(asp, 4);
    adp += __shfl_xor(adp, 1); adp += __shfl_xor(adp, 2); adp += __shfl_xor(adp, 4);
    if (cp == 0 && row < NN) { as2[row] = asp; ad2[row] = adp; }
}

// ---------- Layer 2 aggregation ----------
__global__ __launch_bounds__(256) void k_agg2(
    const int* __restrict__ offs, const int* __restrict__ deg,
    const int* __restrict__ ssrc,
    const float* __restrict__ as2, const float* __restrict__ ad2,
    const float* __restrict__ g2, const float* __restrict__ b2,
    float* __restrict__ out)
{
    int wave = threadIdx.x >> 6;
    int lane = threadIdx.x & 63;
    int node = blockIdx.x * 4 + wave;
    if (node >= NN) return;
    int start = offs[node], cnt = deg[node];
    float adv = ad2[node];

    int li4 = lane & 3, jg = lane >> 2;
    const float4* g2f4 = (const float4*)g2;

    float a0 = 0.f, a1 = 0.f, a2 = 0.f, a3 = 0.f, dsum = 0.f;
    for (int base = 0; base <= cnt; base += 16) {
        int j = base + jg;
        if (j <= cnt) {
            int s = (j < cnt) ? ssrc[start + j] : node;
            float e = as2[s] + adv;
            e = (e > 0.f) ? e : 0.2f * e;
            float w = __expf(e);
            float4 g = g2f4[(size_t)s * 4 + li4];
            a0 += w * g.x; a1 += w * g.y; a2 += w * g.z; a3 += w * g.w;
            if (li4 == 0) dsum += w;
        }
    }
#pragma unroll
    for (int m = 4; m < 64; m <<= 1) {
        a0 += __shfl_xor(a0, m); a1 += __shfl_xor(a1, m);
        a2 += __shfl_xor(a2, m); a3 += __shfl_xor(a3, m);
        dsum += __shfl_xor(dsum, m);
    }
    dsum += __shfl_xor(dsum, 1);
    dsum += __shfl_xor(dsum, 2);   // broadcast denom to all li4

    if (jg == 0) {
        float inv = 1.0f / dsum;
        const float4* b2f4 = (const float4*)b2;
        float4 bb = b2f4[li4];
        float4 o = make_float4(a0 * inv + bb.x, a1 * inv + bb.y,
                               a2 * inv + bb.z, a3 * inv + bb.w);
        ((float4*)out)[(size_t)node * 4 + li4] = o;
    }
}

// ---------- launch ----------
extern "C" void kernel_launch(void* const* d_in, const int* in_sizes, int n_in,
                              void* d_out, int out_size, void* d_ws, size_t ws_size,
                              hipStream_t stream) {
    const float* x   = (const float*)d_in[0];
    const int*   ei  = (const int*)d_in[1];
    const float* W1  = (const float*)d_in[2];
    const float* aS1 = (const float*)d_in[3];
    const float* aD1 = (const float*)d_in[4];
    const float* b1  = (const float*)d_in[5];
    const float* W2  = (const float*)d_in[6];
    const float* aS2 = (const float*)d_in[7];
    const float* aD2 = (const float*)d_in[8];
    const float* b2  = (const float*)d_in[9];

    char* ws = (char*)d_ws;
    size_t off = 0;
    auto alloc = [&](size_t bytes) { void* p = ws + off; off += (bytes + 255) & ~(size_t)255; return p; };

    unsigned short* h1 = (unsigned short*)alloc((size_t)NN * 128 * 2);  // bf16
    unsigned short* h2 = (unsigned short*)alloc((size_t)NN * 128 * 2);  // bf16
    float* as1 = (float*)alloc((size_t)NN * 8 * 4);
    float* ad1 = (float*)alloc((size_t)NN * 8 * 4);
    float* g2  = (float*)alloc((size_t)NN * 16 * 4);
    float* as2 = (float*)alloc((size_t)NN * 4);
    float* ad2 = (float*)alloc((size_t)NN * 4);
    int* deg    = (int*)alloc((size_t)NN * 4);
    int* offs   = (int*)alloc((size_t)NN * 4);
    int* ssrc   = (int*)alloc((size_t)NBK * BCAP * 4);
    unsigned int* packed = (unsigned int*)alloc((size_t)NBK * BCAP * 4);
    int* gcur   = (int*)alloc((size_t)NBK * 4);
    uint4* W1s  = (uint4*)alloc((size_t)2048 * 16);   // swizzled bf16 W1

    hipMemsetAsync(gcur, 0, (size_t)NBK * 4, stream);
    k_bin<<<NCH, 256, 0, stream>>>(ei, gcur, packed);
    k_final<<<NBK, 256, 0, stream>>>(packed, gcur, deg, offs, ssrc);

    k_swizw<<<8, 256, 0, stream>>>(W1, W1s);
    k_gemm1<<<(NN + 63) / 64, 256, 0, stream>>>(x, W1s, aS1, aD1, h1, as1, ad1);
    k_agg1<<<(NN + 3) / 4, 256, 0, stream>>>(offs, deg, ssrc, as1, ad1, h1, b1, h2);
    k_gemm2<<<(NN + 31) / 32, 256, 0, stream>>>(h2, W2, aS2, aD2, g2, as2, ad2);
    k_agg2<<<(NN + 3) / 4, 256, 0, stream>>>(offs, deg, ssrc, as2, ad2, g2, b2,
                                             (float*)d_out);
}

// Round 9
// 199.221 us; speedup vs baseline: 1.1960x; 1.0939x over previous
//
#include <hip/hip_runtime.h>
#include <hip/hip_bf16.h>
#include <math.h>

#define NN 50000
#define NE 800000
#define NBK 196          // buckets = (NN+255)/256, bucket = dst>>8
#define BCAP 5120        // fixed bucket capacity (mean 4096 -> ~16 sigma headroom)
#define CHUNK 8192
#define NCH ((NE + CHUNK - 1) / CHUNK)   // 98
#define APITCH 136       // padded bf16 row pitch for gemm1 A-tile
#define G1BLOCKS ((NN + 63) / 64)        // 782

typedef short bf16x8 __attribute__((ext_vector_type(8)));
typedef float f32x4  __attribute__((ext_vector_type(4)));
typedef float f32x2  __attribute__((ext_vector_type(2)));

// ---------- bf16 pack/unpack helpers (internal storage only) ----------
__device__ __forceinline__ unsigned short f2bf(float f) {
    union { float f; unsigned int i; } v; v.f = f;
    unsigned int x = v.i;
    unsigned int r = (x >> 16) & 1u;          // round-to-nearest-even
    x += 0x7fffu + r;
    return (unsigned short)(x >> 16);
}
__device__ __forceinline__ void un2(unsigned int u, float& a, float& b) {
    union { unsigned int i; float f; } x, y;
    x.i = u << 16; y.i = u & 0xffff0000u;
    a = x.f; b = y.f;
}
__device__ __forceinline__ f32x2 up2(unsigned int u) {
    union { unsigned int i; float f; } x, y;
    x.i = u << 16; y.i = u & 0xffff0000u;
    return (f32x2){x.f, y.f};
}

// ---------- W1 swizzle + gcur zero (runs first) ----------
__global__ __launch_bounds__(256) void k_swizw(const float* __restrict__ W1,
                                               uint4* __restrict__ W1s,
                                               int* __restrict__ gcur) {
    int t = threadIdx.x;
    if (blockIdx.x == 0 && t < NBK) gcur[t] = 0;
    int f = blockIdx.x * 256 + t;             // [0,2048)
    int nt = f >> 8, kc = (f >> 6) & 3, l = f & 63;
    int n  = nt * 16 + (l & 15);
    int k0 = kc * 32 + (l >> 4) * 8;
    unsigned int p[4];
#pragma unroll
    for (int jj = 0; jj < 4; jj++) {
        float v0 = W1[(k0 + 2 * jj) * 128 + n];
        float v1 = W1[(k0 + 2 * jj + 1) * 128 + n];
        p[jj] = (unsigned int)f2bf(v0) | ((unsigned int)f2bf(v1) << 16);
    }
    W1s[f] = make_uint4(p[0], p[1], p[2], p[3]);
}

// ---------- MERGED: edge binning (blocks 0..NCH-1)  ||  layer-1 MFMA GEMM ----------
__global__ __launch_bounds__(256) void k_bin_gemm1(
    const int* __restrict__ ei, int* __restrict__ gcur,
    unsigned int* __restrict__ packed,
    const float* __restrict__ x, const uint4* __restrict__ W1s,
    const float* __restrict__ aS, const float* __restrict__ aD,
    unsigned short* __restrict__ h1, float* __restrict__ as1,
    float* __restrict__ ad1)
{
    __shared__ union {
        struct { int h[NBK]; int bas[NBK]; } bin;
        unsigned short alds[64 * APITCH];          // 34816 B
    } sm;
    int t = threadIdx.x;

    if (blockIdx.x < NCH) {
        // ---------------- bin body ----------------
        int* h = sm.bin.h;
        int* bas = sm.bin.bas;
        if (t < NBK) h[t] = 0;
        __syncthreads();
        int cb = blockIdx.x * CHUNK;
#pragma unroll
        for (int k = 0; k < CHUNK / 256; k++) {
            int i = cb + k * 256 + t;
            if (i < NE) atomicAdd(&h[ei[NE + i] >> 8], 1);
        }
        __syncthreads();
        if (t < NBK) {
            int c = h[t];
            bas[t] = c ? (t * BCAP + atomicAdd(&gcur[t], c)) : 0;
            h[t] = 0;
        }
        __syncthreads();
#pragma unroll
        for (int k = 0; k < CHUNK / 256; k++) {
            int i = cb + k * 256 + t;
            if (i < NE) {
                int s = ei[i], d = ei[NE + i];
                int b = d >> 8;
                int r = atomicAdd(&h[b], 1);
                packed[bas[b] + r] = (unsigned int)s | ((unsigned int)(d & 255) << 16);
            }
        }
        return;
    }

    // ---------------- gemm1 body ----------------
    unsigned short* Alds = sm.alds;
    int w = t >> 6, l = t & 63;
    int rowbase = (blockIdx.x - NCH) * 64;

    {
        const float4* xg = (const float4*)(x + (size_t)rowbase * 128);
#pragma unroll
        for (int i = 0; i < 8; i++) {
            int idx = t + 256 * i;             // float4 id [0,2048)
            int r = idx >> 5, c = (idx & 31) * 4;
            float4 v = make_float4(0.f, 0.f, 0.f, 0.f);
            if (rowbase + r < NN) v = xg[idx];
            unsigned int p0 = (unsigned int)f2bf(v.x) | ((unsigned int)f2bf(v.y) << 16);
            unsigned int p1 = (unsigned int)f2bf(v.z) | ((unsigned int)f2bf(v.w) << 16);
            *(uint2*)&Alds[r * APITCH + c] = make_uint2(p0, p1);
        }
    }

    union BU { uint4 u; bf16x8 v; };
    BU b[2][4];
#pragma unroll
    for (int j = 0; j < 2; j++) {
        int nt = 2 * w + j;
#pragma unroll
        for (int kc = 0; kc < 4; kc++)
            b[j][kc].u = W1s[(nt * 4 + kc) * 64 + l];
    }
    __syncthreads();

    f32x4 acc[4][2];
#pragma unroll
    for (int mt = 0; mt < 4; mt++)
#pragma unroll
        for (int j = 0; j < 2; j++) acc[mt][j] = (f32x4){0.f, 0.f, 0.f, 0.f};

    int mrow = l & 15, quad = l >> 4;
#pragma unroll
    for (int kc = 0; kc < 4; kc++) {
#pragma unroll
        for (int mt = 0; mt < 4; mt++) {
            bf16x8 a = *(const bf16x8*)&Alds[(mt * 16 + mrow) * APITCH + kc * 32 + quad * 8];
            acc[mt][0] = __builtin_amdgcn_mfma_f32_16x16x32_bf16(a, b[0][kc].v, acc[mt][0], 0, 0, 0);
            acc[mt][1] = __builtin_amdgcn_mfma_f32_16x16x32_bf16(a, b[1][kc].v, acc[mt][1], 0, 0, 0);
        }
    }

#pragma unroll
    for (int j = 0; j < 2; j++) {
        int head = 2 * w + j;
        float aSv = aS[head * 16 + mrow];
        float aDv = aD[head * 16 + mrow];
#pragma unroll
        for (int mt = 0; mt < 4; mt++) {
#pragma unroll
            for (int reg = 0; reg < 4; reg++) {
                float s = acc[mt][j][reg] * aSv;
                float d = acc[mt][j][reg] * aDv;
                s += __shfl_xor(s, 1); s += __shfl_xor(s, 2);
                s += __shfl_xor(s, 4); s += __shfl_xor(s, 8);
                d += __shfl_xor(d, 1); d += __shfl_xor(d, 2);
                d += __shfl_xor(d, 4); d += __shfl_xor(d, 8);
                if (mrow == 0) {
                    int grow = rowbase + mt * 16 + quad * 4 + reg;
                    if (grow < NN) {
                        as1[grow * 8 + head] = s;
                        ad1[grow * 8 + head] = d;
                    }
                }
            }
        }
    }

    __syncthreads();   // A reads done; reuse Alds for C transpose
#pragma unroll
    for (int mt = 0; mt < 4; mt++)
#pragma unroll
        for (int j = 0; j < 2; j++) {
            int col = w * 32 + j * 16 + mrow;
#pragma unroll
            for (int reg = 0; reg < 4; reg++) {
                int r = mt * 16 + quad * 4 + reg;
                Alds[r * APITCH + col] = f2bf(acc[mt][j][reg]);
            }
        }
    __syncthreads();
    uint4* hg = (uint4*)h1;   // 16 uint4 per 128-col row
#pragma unroll
    for (int i = 0; i < 4; i++) {
        int idx = t + 256 * i;           // uint4 id [0,1024)
        int r = idx >> 4, ci = idx & 15;
        if (rowbase + r < NN)
            hg[(size_t)(rowbase + r) * 16 + ci] = *(const uint4*)&Alds[r * APITCH + ci * 8];
    }
}

// ---------- per-bucket finalize ----------
__global__ __launch_bounds__(256) void k_final(const unsigned int* __restrict__ packed,
                                               const int* __restrict__ gcur,
                                               int* __restrict__ deg,
                                               int* __restrict__ offs,
                                               int* __restrict__ ssrc) {
    __shared__ unsigned int pk[BCAP + 64];
    __shared__ int osl[BCAP + 64];
    __shared__ int cnt[256], pre[256], cur[256];
    int t = threadIdx.x, b = blockIdx.x;
    int start = b * BCAP;
    int n = gcur[b];
    for (int i = t; i < n; i += 256) pk[i] = packed[start + i];
    cnt[t] = 0;
    __syncthreads();
    for (int i = t; i < n; i += 256) atomicAdd(&cnt[(pk[i] >> 16) & 255], 1);
    __syncthreads();
    int v = cnt[t];
    pre[t] = v;
    __syncthreads();
    for (int off = 1; off < 256; off <<= 1) {
        int u = (t >= off) ? pre[t - off] : 0;
        __syncthreads();
        pre[t] += u;
        __syncthreads();
    }
    int excl = pre[t] - v;
    int dst = b * 256 + t;
    if (dst < NN) { deg[dst] = v; offs[dst] = start + excl; }
    cur[t] = excl;
    __syncthreads();
    for (int i = t; i < n; i += 256) {
        unsigned int p = pk[i];
        int r = atomicAdd(&cur[(p >> 16) & 255], 1);
        osl[r] = (int)(p & 0xffffu);
    }
    __syncthreads();
    for (int i = t; i < n; i += 256) ssrc[start + i] = osl[i];
}

// ---------- Layer 1 aggregation: lane = jg*8 + li, li == head, 32B/lane ----------
__global__ __launch_bounds__(256) void k_agg1(
    const int* __restrict__ offs, const int* __restrict__ deg,
    const int* __restrict__ ssrc,
    const float* __restrict__ as1, const float* __restrict__ ad1,
    const unsigned short* __restrict__ h1, const float* __restrict__ b1,
    unsigned short* __restrict__ h2)
{
    int wave = threadIdx.x >> 6;
    int lane = threadIdx.x & 63;
    int node = blockIdx.x * 4 + wave;
    if (node >= NN) return;
    int start = offs[node], cnt = deg[node];

    int li = lane & 7, jg = lane >> 3;   // li = head, covers cols [li*16, li*16+16)
    float adv = ad1[node * 8 + li];

    const uint4* h1u4 = (const uint4*)h1;
    f32x2 acc[8];
#pragma unroll
    for (int i = 0; i < 8; i++) acc[i] = (f32x2){0.f, 0.f};
    float dsum = 0.f;

    for (int base = 0; base <= cnt; base += 32) {    // 4 x 8 edges in flight
#pragma unroll
        for (int u = 0; u < 4; u++) {
            int j = base + u * 8 + jg;
            if (j <= cnt) {
                int s = (j < cnt) ? ssrc[start + j] : node;   // j==cnt -> self loop
                float e = as1[s * 8 + li] + adv;
                e = (e > 0.f) ? e : 0.2f * e;
                float w = __expf(e);
                uint4 ha = h1u4[(size_t)s * 16 + 2 * li];
                uint4 hb = h1u4[(size_t)s * 16 + 2 * li + 1];
                f32x2 w2 = (f32x2){w, w};
                acc[0] += w2 * up2(ha.x); acc[1] += w2 * up2(ha.y);
                acc[2] += w2 * up2(ha.z); acc[3] += w2 * up2(ha.w);
                acc[4] += w2 * up2(hb.x); acc[5] += w2 * up2(hb.y);
                acc[6] += w2 * up2(hb.z); acc[7] += w2 * up2(hb.w);
                dsum += w;
            }
        }
    }

    // butterfly over the 8 jg groups (lanes with same li)
#pragma unroll
    for (int i = 0; i < 8; i++) {
        acc[i].x += __shfl_xor(acc[i].x, 8);  acc[i].y += __shfl_xor(acc[i].y, 8);
        acc[i].x += __shfl_xor(acc[i].x, 16); acc[i].y += __shfl_xor(acc[i].y, 16);
        acc[i].x += __shfl_xor(acc[i].x, 32); acc[i].y += __shfl_xor(acc[i].y, 32);
    }
    dsum += __shfl_xor(dsum, 8);
    dsum += __shfl_xor(dsum, 16);
    dsum += __shfl_xor(dsum, 32);

    if (jg == 0) {
        float inv = 1.0f / dsum;
        int c0 = li * 16;
        float v[16];
#pragma unroll
        for (int i = 0; i < 8; i++) {
            float v0 = acc[i].x * inv + b1[c0 + 2 * i];
            float v1 = acc[i].y * inv + b1[c0 + 2 * i + 1];
            v[2 * i]     = (v0 > 0.f) ? v0 : (__expf(v0) - 1.0f);   // ELU
            v[2 * i + 1] = (v1 > 0.f) ? v1 : (__expf(v1) - 1.0f);
        }
        uint4 o0, o1;
        o0.x = (unsigned int)f2bf(v[0])  | ((unsigned int)f2bf(v[1])  << 16);
        o0.y = (unsigned int)f2bf(v[2])  | ((unsigned int)f2bf(v[3])  << 16);
        o0.z = (unsigned int)f2bf(v[4])  | ((unsigned int)f2bf(v[5])  << 16);
        o0.w = (unsigned int)f2bf(v[6])  | ((unsigned int)f2bf(v[7])  << 16);
        o1.x = (unsigned int)f2bf(v[8])  | ((unsigned int)f2bf(v[9])  << 16);
        o1.y = (unsigned int)f2bf(v[10]) | ((unsigned int)f2bf(v[11]) << 16);
        o1.z = (unsigned int)f2bf(v[12]) | ((unsigned int)f2bf(v[13]) << 16);
        o1.w = (unsigned int)f2bf(v[14]) | ((unsigned int)f2bf(v[15]) << 16);
        ((uint4*)h2)[(size_t)node * 16 + 2 * li] = o0;
        ((uint4*)h2)[(size_t)node * 16 + 2 * li + 1] = o1;
    }
}

// ---------- Layer 2 GEMM ----------
__global__ __launch_bounds__(256) void k_gemm2(
    const unsigned short* __restrict__ h2,   // [NN,128] bf16
    const float* __restrict__ W2,            // [128,16] fp32
    const float* __restrict__ aS2,           // [16]
    const float* __restrict__ aD2,           // [16]
    float* __restrict__ g2,                  // [NN,16]
    float* __restrict__ as2, float* __restrict__ ad2)
{
    __shared__ float Wl[128 * 16];     // 8 KB
    __shared__ float xl[32 * 129];     // padded
    __shared__ float aSf[16], aDf[16];
    int t = threadIdx.x;

    for (int i = t; i < 2048; i += 256) Wl[i] = W2[i];
    if (t < 16) { aSf[t] = aS2[t]; aDf[t] = aD2[t]; }

    int rowbase = blockIdx.x * 32;
    for (int i = t; i < 2048; i += 256) {        // 32 rows * 64 uints
        int row = rowbase + (i >> 6);
        unsigned int u = (row < NN) ? ((const unsigned int*)h2)[(size_t)rowbase * 64 + i] : 0u;
        float a, b; un2(u, a, b);
        int lin = 2 * i;
        int rr = lin >> 7, kk = lin & 127;
        xl[rr * 129 + kk] = a;
        xl[rr * 129 + kk + 1] = b;
    }
    __syncthreads();

    int r = t >> 3, cp = t & 7;
    int row = rowbase + r;
    float a0 = 0.f, a1 = 0.f;
    const float* xrow = &xl[r * 129];
#pragma unroll 4
    for (int k = 0; k < 128; k++) {
        float xv = xrow[k];
        a0 += xv * Wl[k * 16 + 2 * cp];
        a1 += xv * Wl[k * 16 + 2 * cp + 1];
    }
    if (row < NN) ((float2*)g2)[(size_t)row * 8 + cp] = make_float2(a0, a1);

    float asp = a0 * aSf[2 * cp] + a1 * aSf[2 * cp + 1];
    float adp = a0 * aDf[2 * cp] + a1 * aDf[2 * cp + 1];
    asp += __shfl_xor(asp, 1); asp += __shfl_xor(asp, 2); asp += __shfl_xor(asp, 4);
    adp += __shfl_xor(adp, 1); adp += __shfl_xor(adp, 2); adp += __shfl_xor(adp, 4);
    if (cp == 0 && row < NN) { as2[row] = asp; ad2[row] = adp; }
}

// ---------- Layer 2 aggregation: 32 edges in flight ----------
__global__ __launch_bounds__(256) void k_agg2(
    const int* __restrict__ offs, const int* __restrict__ deg,
    const int* __restrict__ ssrc,
    const float* __restrict__ as2, const float* __restrict__ ad2,
    const float* __restrict__ g2, const float* __restrict__ b2,
    float* __restrict__ out)
{
    int wave = threadIdx.x >> 6;
    int lane = threadIdx.x & 63;
    int node = blockIdx.x * 4 + wave;
    if (node >= NN) return;
    int start = offs[node], cnt = deg[node];
    float adv = ad2[node];

    int li4 = lane & 3, jg = lane >> 2;
    const float4* g2f4 = (const float4*)g2;

    float a0 = 0.f, a1 = 0.f, a2 = 0.f, a3 = 0.f, dsum = 0.f;
    for (int base = 0; base <= cnt; base += 32) {
#pragma unroll
        for (int u = 0; u < 2; u++) {
            int j = base + u * 16 + jg;
            if (j <= cnt) {
                int s = (j < cnt) ? ssrc[start + j] : node;
                float e = as2[s] + adv;
                e = (e > 0.f) ? e : 0.2f * e;
                float w = __expf(e);
                float4 g = g2f4[(size_t)s * 4 + li4];
                a0 += w * g.x; a1 += w * g.y; a2 += w * g.z; a3 += w * g.w;
                if (li4 == 0) dsum += w;
            }
        }
    }
#pragma unroll
    for (int m = 4; m < 64; m <<= 1) {
        a0 += __shfl_xor(a0, m); a1 += __shfl_xor(a1, m);
        a2 += __shfl_xor(a2, m); a3 += __shfl_xor(a3, m);
        dsum += __shfl_xor(dsum, m);
    }
    dsum += __shfl_xor(dsum, 1);
    dsum += __shfl_xor(dsum, 2);   // broadcast denom to all li4

    if (jg == 0) {
        float inv = 1.0f / dsum;
        const float4* b2f4 = (const float4*)b2;
        float4 bb = b2f4[li4];
        float4 o = make_float4(a0 * inv + bb.x, a1 * inv + bb.y,
                               a2 * inv + bb.z, a3 * inv + bb.w);
        ((float4*)out)[(size_t)node * 4 + li4] = o;
    }
}

// ---------- launch ----------
extern "C" void kernel_launch(void* const* d_in, const int* in_sizes, int n_in,
                              void* d_out, int out_size, void* d_ws, size_t ws_size,
                              hipStream_t stream) {
    const float* x   = (const float*)d_in[0];
    const int*   ei  = (const int*)d_in[1];
    const float* W1  = (const float*)d_in[2];
    const float* aS1 = (const float*)d_in[3];
    const float* aD1 = (const float*)d_in[4];
    const float* b1  = (const float*)d_in[5];
    const float* W2  = (const float*)d_in[6];
    const float* aS2 = (const float*)d_in[7];
    const float* aD2 = (const float*)d_in[8];
    const float* b2  = (const float*)d_in[9];

    char* ws = (char*)d_ws;
    size_t off = 0;
    auto alloc = [&](size_t bytes) { void* p = ws + off; off += (bytes + 255) & ~(size_t)255; return p; };

    unsigned short* h1 = (unsigned short*)alloc((size_t)NN * 128 * 2);  // bf16
    unsigned short* h2 = (unsigned short*)alloc((size_t)NN * 128 * 2);  // bf16
    float* as1 = (float*)alloc((size_t)NN * 8 * 4);
    float* ad1 = (float*)alloc((size_t)NN * 8 * 4);
    float* g2  = (float*)alloc((size_t)NN * 16 * 4);
    float* as2 = (float*)alloc((size_t)NN * 4);
    float* ad2 = (float*)alloc((size_t)NN * 4);
    int* deg    = (int*)alloc((size_t)NN * 4);
    int* offs   = (int*)alloc((size_t)NN * 4);
    int* ssrc   = (int*)alloc((size_t)NBK * BCAP * 4);
    unsigned int* packed = (unsigned int*)alloc((size_t)NBK * BCAP * 4);
    int* gcur   = (int*)alloc((size_t)NBK * 4);
    uint4* W1s  = (uint4*)alloc((size_t)2048 * 16);   // swizzled bf16 W1

    k_swizw<<<8, 256, 0, stream>>>(W1, W1s, gcur);
    k_bin_gemm1<<<NCH + G1BLOCKS, 256, 0, stream>>>(ei, gcur, packed,
                                                    x, W1s, aS1, aD1, h1, as1, ad1);
    k_final<<<NBK, 256, 0, stream>>>(packed, gcur, deg, offs, ssrc);
    k_agg1<<<(NN + 3) / 4, 256, 0, stream>>>(offs, deg, ssrc, as1, ad1, h1, b1, h2);
    k_gemm2<<<(NN + 31) / 32, 256, 0, stream>>>(h2, W2, aS2, aD2, g2, as2, ad2);
    k_agg2<<<(NN + 3) / 4, 256, 0, stream>>>(offs, deg, ssrc, as2, ad2, g2, b2,
                                             (float*)d_out);
}

// Round 10
// 188.837 us; speedup vs baseline: 1.2618x; 1.0550x over previous
//
#include <hip/hip_runtime.h>
#include <hip/hip_bf16.h>
#include <math.h>

#define NN 50000
#define NE 800000
#define NBK 196          // buckets = (NN+255)/256, bucket = dst>>8
#define BCAP 5120        // fixed bucket capacity (edges + 256 self-loops fits)
#define CHUNK 8192
#define NCH ((NE + CHUNK - 1) / CHUNK)   // 98
#define APITCH 136       // padded bf16 row pitch for gemm1 A-tile
#define G1BLOCKS ((NN + 63) / 64)        // 782

typedef short bf16x8 __attribute__((ext_vector_type(8)));
typedef float f32x4  __attribute__((ext_vector_type(4)));
typedef float f32x2  __attribute__((ext_vector_type(2)));

// ---------- bf16 pack/unpack helpers (internal storage only) ----------
__device__ __forceinline__ unsigned short f2bf(float f) {
    union { float f; unsigned int i; } v; v.f = f;
    unsigned int x = v.i;
    unsigned int r = (x >> 16) & 1u;          // round-to-nearest-even
    x += 0x7fffu + r;
    return (unsigned short)(x >> 16);
}
__device__ __forceinline__ void un2(unsigned int u, float& a, float& b) {
    union { unsigned int i; float f; } x, y;
    x.i = u << 16; y.i = u & 0xffff0000u;
    a = x.f; b = y.f;
}
__device__ __forceinline__ f32x2 up2(unsigned int u) {
    union { unsigned int i; float f; } x, y;
    x.i = u << 16; y.i = u & 0xffff0000u;
    return (f32x2){x.f, y.f};
}

// ---------- W1/W2 swizzle + gcur zero (runs first; 9 blocks) ----------
__global__ __launch_bounds__(256) void k_swizw(const float* __restrict__ W1,
                                               const float* __restrict__ W2,
                                               uint4* __restrict__ W1s,
                                               uint4* __restrict__ W2s,
                                               int* __restrict__ gcur) {
    int t = threadIdx.x;
    if (blockIdx.x == 8) {
        if (t < NBK) gcur[t] = 0;
        // W2 -> B fragments (bf16): frag f = kc*64 + l, B[k=kc*32+(l>>4)*8+j][n=l&15]
        int kc = t >> 6, l = t & 63;
        int n = l & 15, k0 = kc * 32 + (l >> 4) * 8;
        unsigned int p[4];
#pragma unroll
        for (int jj = 0; jj < 4; jj++) {
            float v0 = W2[(k0 + 2 * jj) * 16 + n];
            float v1 = W2[(k0 + 2 * jj + 1) * 16 + n];
            p[jj] = (unsigned int)f2bf(v0) | ((unsigned int)f2bf(v1) << 16);
        }
        W2s[t] = make_uint4(p[0], p[1], p[2], p[3]);
        return;
    }
    int f = blockIdx.x * 256 + t;             // [0,2048)
    int nt = f >> 8, kc = (f >> 6) & 3, l = f & 63;
    int n  = nt * 16 + (l & 15);
    int k0 = kc * 32 + (l >> 4) * 8;
    unsigned int p[4];
#pragma unroll
    for (int jj = 0; jj < 4; jj++) {
        float v0 = W1[(k0 + 2 * jj) * 128 + n];
        float v1 = W1[(k0 + 2 * jj + 1) * 128 + n];
        p[jj] = (unsigned int)f2bf(v0) | ((unsigned int)f2bf(v1) << 16);
    }
    W1s[f] = make_uint4(p[0], p[1], p[2], p[3]);
}

// ---------- MERGED: edge binning (blocks 0..NCH-1)  ||  layer-1 MFMA GEMM ----------
__global__ __launch_bounds__(256) void k_bin_gemm1(
    const int* __restrict__ ei, int* __restrict__ gcur,
    unsigned int* __restrict__ packed,
    const float* __restrict__ x, const uint4* __restrict__ W1s,
    const float* __restrict__ aS, const float* __restrict__ aD,
    unsigned short* __restrict__ h1, float* __restrict__ as1,
    float* __restrict__ ad1)
{
    __shared__ union {
        struct { int h[NBK]; int bas[NBK]; } bin;
        unsigned short alds[64 * APITCH];          // 34816 B
    } sm;
    int t = threadIdx.x;

    if (blockIdx.x < NCH) {
        int* h = sm.bin.h;
        int* bas = sm.bin.bas;
        if (t < NBK) h[t] = 0;
        __syncthreads();
        int cb = blockIdx.x * CHUNK;
#pragma unroll
        for (int k = 0; k < CHUNK / 256; k++) {
            int i = cb + k * 256 + t;
            if (i < NE) atomicAdd(&h[ei[NE + i] >> 8], 1);
        }
        __syncthreads();
        if (t < NBK) {
            int c = h[t];
            bas[t] = c ? (t * BCAP + atomicAdd(&gcur[t], c)) : 0;
            h[t] = 0;
        }
        __syncthreads();
#pragma unroll
        for (int k = 0; k < CHUNK / 256; k++) {
            int i = cb + k * 256 + t;
            if (i < NE) {
                int s = ei[i], d = ei[NE + i];
                int b = d >> 8;
                int r = atomicAdd(&h[b], 1);
                packed[bas[b] + r] = (unsigned int)s | ((unsigned int)(d & 255) << 16);
            }
        }
        return;
    }

    // ---------------- gemm1 body ----------------
    unsigned short* Alds = sm.alds;
    int w = t >> 6, l = t & 63;
    int rowbase = (blockIdx.x - NCH) * 64;

    {
        const float4* xg = (const float4*)(x + (size_t)rowbase * 128);
#pragma unroll
        for (int i = 0; i < 8; i++) {
            int idx = t + 256 * i;             // float4 id [0,2048)
            int r = idx >> 5, c = (idx & 31) * 4;
            float4 v = make_float4(0.f, 0.f, 0.f, 0.f);
            if (rowbase + r < NN) v = xg[idx];
            unsigned int p0 = (unsigned int)f2bf(v.x) | ((unsigned int)f2bf(v.y) << 16);
            unsigned int p1 = (unsigned int)f2bf(v.z) | ((unsigned int)f2bf(v.w) << 16);
            *(uint2*)&Alds[r * APITCH + c] = make_uint2(p0, p1);
        }
    }

    union BU { uint4 u; bf16x8 v; };
    BU b[2][4];
#pragma unroll
    for (int j = 0; j < 2; j++) {
        int nt = 2 * w + j;
#pragma unroll
        for (int kc = 0; kc < 4; kc++)
            b[j][kc].u = W1s[(nt * 4 + kc) * 64 + l];
    }
    __syncthreads();

    f32x4 acc[4][2];
#pragma unroll
    for (int mt = 0; mt < 4; mt++)
#pragma unroll
        for (int j = 0; j < 2; j++) acc[mt][j] = (f32x4){0.f, 0.f, 0.f, 0.f};

    int mrow = l & 15, quad = l >> 4;
#pragma unroll
    for (int kc = 0; kc < 4; kc++) {
#pragma unroll
        for (int mt = 0; mt < 4; mt++) {
            bf16x8 a = *(const bf16x8*)&Alds[(mt * 16 + mrow) * APITCH + kc * 32 + quad * 8];
            acc[mt][0] = __builtin_amdgcn_mfma_f32_16x16x32_bf16(a, b[0][kc].v, acc[mt][0], 0, 0, 0);
            acc[mt][1] = __builtin_amdgcn_mfma_f32_16x16x32_bf16(a, b[1][kc].v, acc[mt][1], 0, 0, 0);
        }
    }

#pragma unroll
    for (int j = 0; j < 2; j++) {
        int head = 2 * w + j;
        float aSv = aS[head * 16 + mrow];
        float aDv = aD[head * 16 + mrow];
#pragma unroll
        for (int mt = 0; mt < 4; mt++) {
#pragma unroll
            for (int reg = 0; reg < 4; reg++) {
                float s = acc[mt][j][reg] * aSv;
                float d = acc[mt][j][reg] * aDv;
                s += __shfl_xor(s, 1); s += __shfl_xor(s, 2);
                s += __shfl_xor(s, 4); s += __shfl_xor(s, 8);
                d += __shfl_xor(d, 1); d += __shfl_xor(d, 2);
                d += __shfl_xor(d, 4); d += __shfl_xor(d, 8);
                if (mrow == 0) {
                    int grow = rowbase + mt * 16 + quad * 4 + reg;
                    if (grow < NN) {
                        as1[grow * 8 + head] = s;
                        ad1[grow * 8 + head] = d;
                    }
                }
            }
        }
    }

    __syncthreads();   // A reads done; reuse Alds for C transpose
#pragma unroll
    for (int mt = 0; mt < 4; mt++)
#pragma unroll
        for (int j = 0; j < 2; j++) {
            int col = w * 32 + j * 16 + mrow;
#pragma unroll
            for (int reg = 0; reg < 4; reg++) {
                int r = mt * 16 + quad * 4 + reg;
                Alds[r * APITCH + col] = f2bf(acc[mt][j][reg]);
            }
        }
    __syncthreads();
    uint4* hg = (uint4*)h1;   // 16 uint4 per 128-col row
#pragma unroll
    for (int i = 0; i < 4; i++) {
        int idx = t + 256 * i;           // uint4 id [0,1024)
        int r = idx >> 4, ci = idx & 15;
        if (rowbase + r < NN)
            hg[(size_t)(rowbase + r) * 16 + ci] = *(const uint4*)&Alds[r * APITCH + ci * 8];
    }
}

// ---------- per-bucket finalize: rank by dst, APPEND SELF-LOOP per node ----------
__global__ __launch_bounds__(256) void k_final(const unsigned int* __restrict__ packed,
                                               const int* __restrict__ gcur,
                                               int* __restrict__ deg,
                                               int* __restrict__ offs,
                                               int* __restrict__ ssrc) {
    __shared__ unsigned int pk[BCAP];
    __shared__ int osl[BCAP];
    __shared__ int cnt[256], pre[256], cur[256];
    int t = threadIdx.x, b = blockIdx.x;
    int start = b * BCAP;
    int n = gcur[b];
    int nnodes = NN - b * 256; if (nnodes > 256) nnodes = 256;
    for (int i = t; i < n; i += 256) pk[i] = packed[start + i];
    cnt[t] = 0;
    __syncthreads();
    for (int i = t; i < n; i += 256) atomicAdd(&cnt[(pk[i] >> 16) & 255], 1);
    __syncthreads();
    int v = cnt[t];
    pre[t] = v;
    __syncthreads();
    for (int off = 1; off < 256; off <<= 1) {
        int u = (t >= off) ? pre[t - off] : 0;
        __syncthreads();
        pre[t] += u;
        __syncthreads();
    }
    int excl = pre[t] - v;
    int mybase = excl + t;               // +t self-slots of earlier nodes
    int dst = b * 256 + t;
    if (dst < NN) {
        deg[dst] = v + 1;                // cnt2: edges + self
        offs[dst] = start + mybase;
        osl[mybase + v] = dst;           // self-loop at segment end
    }
    cur[t] = mybase;
    __syncthreads();
    for (int i = t; i < n; i += 256) {
        unsigned int p = pk[i];
        int r = atomicAdd(&cur[(p >> 16) & 255], 1);
        osl[r] = (int)(p & 0xffffu);
    }
    __syncthreads();
    int n2 = n + nnodes;
    for (int i = t; i < n2; i += 256) ssrc[start + i] = osl[i];
}

// ---------- Layer 1 aggregation: lane = jg*8 + li, li == head, 32B/lane ----------
__global__ __launch_bounds__(256) void k_agg1(
    const int* __restrict__ offs, const int* __restrict__ deg,
    const int* __restrict__ ssrc,
    const float* __restrict__ as1, const float* __restrict__ ad1,
    const unsigned short* __restrict__ h1, const float* __restrict__ b1,
    unsigned short* __restrict__ h2)
{
    int wave = threadIdx.x >> 6;
    int lane = threadIdx.x & 63;
    int node = blockIdx.x * 4 + wave;
    if (node >= NN) return;
    int start = offs[node], cnt2 = deg[node];   // self-loop included

    int li = lane & 7, jg = lane >> 3;   // li = head, covers cols [li*16, li*16+16)
    float adv = ad1[node * 8 + li];

    const uint4* h1u4 = (const uint4*)h1;
    f32x2 acc[8];
#pragma unroll
    for (int i = 0; i < 8; i++) acc[i] = (f32x2){0.f, 0.f};
    float dsum = 0.f;

    for (int base = 0; base < cnt2; base += 32) {    // 4 x 8 edges in flight
#pragma unroll
        for (int u = 0; u < 4; u++) {
            int j = base + u * 8 + jg;
            if (j < cnt2) {
                int s = ssrc[start + j];
                float e = as1[s * 8 + li] + adv;
                e = (e > 0.f) ? e : 0.2f * e;
                float w = __expf(e);
                uint4 ha = h1u4[(size_t)s * 16 + 2 * li];
                uint4 hb = h1u4[(size_t)s * 16 + 2 * li + 1];
                f32x2 w2 = (f32x2){w, w};
                acc[0] += w2 * up2(ha.x); acc[1] += w2 * up2(ha.y);
                acc[2] += w2 * up2(ha.z); acc[3] += w2 * up2(ha.w);
                acc[4] += w2 * up2(hb.x); acc[5] += w2 * up2(hb.y);
                acc[6] += w2 * up2(hb.z); acc[7] += w2 * up2(hb.w);
                dsum += w;
            }
        }
    }

    // butterfly over the 8 jg groups (lanes with same li)
#pragma unroll
    for (int i = 0; i < 8; i++) {
        acc[i].x += __shfl_xor(acc[i].x, 8);  acc[i].y += __shfl_xor(acc[i].y, 8);
        acc[i].x += __shfl_xor(acc[i].x, 16); acc[i].y += __shfl_xor(acc[i].y, 16);
        acc[i].x += __shfl_xor(acc[i].x, 32); acc[i].y += __shfl_xor(acc[i].y, 32);
    }
    dsum += __shfl_xor(dsum, 8);
    dsum += __shfl_xor(dsum, 16);
    dsum += __shfl_xor(dsum, 32);

    if (jg == 0) {
        float inv = 1.0f / dsum;
        int c0 = li * 16;
        float v[16];
#pragma unroll
        for (int i = 0; i < 8; i++) {
            float v0 = acc[i].x * inv + b1[c0 + 2 * i];
            float v1 = acc[i].y * inv + b1[c0 + 2 * i + 1];
            v[2 * i]     = (v0 > 0.f) ? v0 : (__expf(v0) - 1.0f);   // ELU
            v[2 * i + 1] = (v1 > 0.f) ? v1 : (__expf(v1) - 1.0f);
        }
        uint4 o0, o1;
        o0.x = (unsigned int)f2bf(v[0])  | ((unsigned int)f2bf(v[1])  << 16);
        o0.y = (unsigned int)f2bf(v[2])  | ((unsigned int)f2bf(v[3])  << 16);
        o0.z = (unsigned int)f2bf(v[4])  | ((unsigned int)f2bf(v[5])  << 16);
        o0.w = (unsigned int)f2bf(v[6])  | ((unsigned int)f2bf(v[7])  << 16);
        o1.x = (unsigned int)f2bf(v[8])  | ((unsigned int)f2bf(v[9])  << 16);
        o1.y = (unsigned int)f2bf(v[10]) | ((unsigned int)f2bf(v[11]) << 16);
        o1.z = (unsigned int)f2bf(v[12]) | ((unsigned int)f2bf(v[13]) << 16);
        o1.w = (unsigned int)f2bf(v[14]) | ((unsigned int)f2bf(v[15]) << 16);
        ((uint4*)h2)[(size_t)node * 16 + 2 * li] = o0;
        ((uint4*)h2)[(size_t)node * 16 + 2 * li + 1] = o1;
    }
}

// ---------- Layer 2 GEMM via MFMA: g2 = h2 @ W2 (bf16), no LDS ----------
// 4 waves x 16 rows per block. A loaded straight from h2; C layout col=l&15, row=quad*4+reg.
__global__ __launch_bounds__(256) void k_gemm2(
    const unsigned short* __restrict__ h2,   // [NN,128] bf16
    const uint4* __restrict__ W2s,           // 256 bf16 B-fragments
    const float* __restrict__ aS2, const float* __restrict__ aD2,
    float* __restrict__ g2, float* __restrict__ as2, float* __restrict__ ad2)
{
    int t = threadIdx.x;
    int w = t >> 6, l = t & 63;
    int rowbase = blockIdx.x * 64 + w * 16;
    int arow = l & 15, quad = l >> 4;
    int row = rowbase + arow; if (row >= NN) row = NN - 1;   // clamp (discarded on store)

    union BU { uint4 u; bf16x8 v; };
    f32x4 acc = (f32x4){0.f, 0.f, 0.f, 0.f};
#pragma unroll
    for (int kc = 0; kc < 4; kc++) {
        bf16x8 a = *(const bf16x8*)&h2[(size_t)row * 128 + kc * 32 + quad * 8];
        BU b; b.u = W2s[kc * 64 + l];
        acc = __builtin_amdgcn_mfma_f32_16x16x32_bf16(a, b.v, acc, 0, 0, 0);
    }

    int col = l & 15;
    float aSv = aS2[col], aDv = aD2[col];
#pragma unroll
    for (int reg = 0; reg < 4; reg++) {
        int grow = rowbase + quad * 4 + reg;
        if (grow < NN) g2[(size_t)grow * 16 + col] = acc[reg];
        float s = acc[reg] * aSv;
        float d = acc[reg] * aDv;
        s += __shfl_xor(s, 1); s += __shfl_xor(s, 2);
        s += __shfl_xor(s, 4); s += __shfl_xor(s, 8);
        d += __shfl_xor(d, 1); d += __shfl_xor(d, 2);
        d += __shfl_xor(d, 4); d += __shfl_xor(d, 8);
        if (col == 0 && grow < NN) { as2[grow] = s; ad2[grow] = d; }
    }
}

// ---------- Layer 2 aggregation: 32 edges in flight ----------
__global__ __launch_bounds__(256) void k_agg2(
    const int* __restrict__ offs, const int* __restrict__ deg,
    const int* __restrict__ ssrc,
    const float* __restrict__ as2, const float* __restrict__ ad2,
    const float* __restrict__ g2, const float* __restrict__ b2,
    float* __restrict__ out)
{
    int wave = threadIdx.x >> 6;
    int lane = threadIdx.x & 63;
    int node = blockIdx.x * 4 + wave;
    if (node >= NN) return;
    int start = offs[node], cnt2 = deg[node];   // self-loop included
    float adv = ad2[node];

    int li4 = lane & 3, jg = lane >> 2;
    const float4* g2f4 = (const float4*)g2;

    float a0 = 0.f, a1 = 0.f, a2 = 0.f, a3 = 0.f, dsum = 0.f;
    for (int base = 0; base < cnt2; base += 32) {
#pragma unroll
        for (int u = 0; u < 2; u++) {
            int j = base + u * 16 + jg;
            if (j < cnt2) {
                int s = ssrc[start + j];
                float e = as2[s] + adv;
                e = (e > 0.f) ? e : 0.2f * e;
                float w = __expf(e);
                float4 g = g2f4[(size_t)s * 4 + li4];
                a0 += w * g.x; a1 += w * g.y; a2 += w * g.z; a3 += w * g.w;
                if (li4 == 0) dsum += w;
            }
        }
    }
#pragma unroll
    for (int m = 4; m < 64; m <<= 1) {
        a0 += __shfl_xor(a0, m); a1 += __shfl_xor(a1, m);
        a2 += __shfl_xor(a2, m); a3 += __shfl_xor(a3, m);
        dsum += __shfl_xor(dsum, m);
    }
    dsum += __shfl_xor(dsum, 1);
    dsum += __shfl_xor(dsum, 2);   // broadcast denom to all li4

    if (jg == 0) {
        float inv = 1.0f / dsum;
        const float4* b2f4 = (const float4*)b2;
        float4 bb = b2f4[li4];
        float4 o = make_float4(a0 * inv + bb.x, a1 * inv + bb.y,
                               a2 * inv + bb.z, a3 * inv + bb.w);
        ((float4*)out)[(size_t)node * 4 + li4] = o;
    }
}

// ---------- launch ----------
extern "C" void kernel_launch(void* const* d_in, const int* in_sizes, int n_in,
                              void* d_out, int out_size, void* d_ws, size_t ws_size,
                              hipStream_t stream) {
    const float* x   = (const float*)d_in[0];
    const int*   ei  = (const int*)d_in[1];
    const float* W1  = (const float*)d_in[2];
    const float* aS1 = (const float*)d_in[3];
    const float* aD1 = (const float*)d_in[4];
    const float* b1  = (const float*)d_in[5];
    const float* W2  = (const float*)d_in[6];
    const float* aS2 = (const float*)d_in[7];
    const float* aD2 = (const float*)d_in[8];
    const float* b2  = (const float*)d_in[9];

    char* ws = (char*)d_ws;
    size_t off = 0;
    auto alloc = [&](size_t bytes) { void* p = ws + off; off += (bytes + 255) & ~(size_t)255; return p; };

    unsigned short* h1 = (unsigned short*)alloc((size_t)NN * 128 * 2);  // bf16
    unsigned short* h2 = (unsigned short*)alloc((size_t)NN * 128 * 2);  // bf16
    float* as1 = (float*)alloc((size_t)NN * 8 * 4);
    float* ad1 = (float*)alloc((size_t)NN * 8 * 4);
    float* g2  = (float*)alloc((size_t)NN * 16 * 4);
    float* as2 = (float*)alloc((size_t)NN * 4);
    float* ad2 = (float*)alloc((size_t)NN * 4);
    int* deg    = (int*)alloc((size_t)NN * 4);
    int* offs   = (int*)alloc((size_t)NN * 4);
    int* ssrc   = (int*)alloc((size_t)NBK * BCAP * 4);
    unsigned int* packed = (unsigned int*)alloc((size_t)NBK * BCAP * 4);
    int* gcur   = (int*)alloc((size_t)NBK * 4);
    uint4* W1s  = (uint4*)alloc((size_t)2048 * 16);   // swizzled bf16 W1
    uint4* W2s  = (uint4*)alloc((size_t)256 * 16);    // swizzled bf16 W2

    k_swizw<<<9, 256, 0, stream>>>(W1, W2, W1s, W2s, gcur);
    k_bin_gemm1<<<NCH + G1BLOCKS, 256, 0, stream>>>(ei, gcur, packed,
                                                    x, W1s, aS1, aD1, h1, as1, ad1);
    k_final<<<NBK, 256, 0, stream>>>(packed, gcur, deg, offs, ssrc);
    k_agg1<<<(NN + 3) / 4, 256, 0, stream>>>(offs, deg, ssrc, as1, ad1, h1, b1, h2);
    k_gemm2<<<(NN + 63) / 64, 256, 0, stream>>>(h2, W2s, aS2, aD2, g2, as2, ad2);
    k_agg2<<<(NN + 3) / 4, 256, 0, stream>>>(offs, deg, ssrc, as2, ad2, g2, b2,
                                             (float*)d_out);
}